// Round 6
// baseline (1622.191 us; speedup 1.0000x reference)
//
#include <hip/hip_runtime.h>
#include <stdint.h>

#define KVOL 27
#define CIN  32
#define COUT 64
#define RB   32          // output rows per bin (5-bit rowlocal)
#define WPG  2           // waves per workgroup (independent; no __syncthreads)
#define TSTRIDE 66       // tile row stride in floats (bank-spread)
#define SCAN_CHUNK 4096

typedef __attribute__((ext_vector_type(8))) short bf16x8;
typedef __attribute__((ext_vector_type(4))) float f32x4;
typedef __attribute__((ext_vector_type(4))) uint32_t u32x4;

__device__ __forceinline__ ushort f2bf(float f) {
  uint32_t u = __float_as_uint(f);
  u += 0x7FFFu + ((u >> 16) & 1u);   // RNE
  return (ushort)(u >> 16);
}

__device__ __forceinline__ uint32_t cvtpk(float lo, float hi) {
  uint32_t r;
  asm("v_cvt_pk_bf16_f32 %0, %1, %2" : "=v"(r) : "v"(lo), "v"(hi));
  return r;
}

// ---------------------------------------------------------------------------
// weights fp32 [KVOL][CIN][COUT] -> bf16 B-frag layout kernT[ko][ct][col16][k32]
// (verified rounds 3-5)
// ---------------------------------------------------------------------------
__global__ __launch_bounds__(256) void kern_cvt_kernel(const float* __restrict__ kern,
                                                       ushort* __restrict__ kernT) {
  int tid = blockIdx.x * 256 + threadIdx.x;
  int kc   = tid & 3;
  int colq = (tid >> 2) & 15;
  int ct   = (tid >> 6) & 3;
  int ko   = tid >> 8;
  if (ko >= KVOL) return;
  const float* src = kern + (size_t)ko * CIN * COUT + ct * 16 + colq;
  ushort tmp[8];
#pragma unroll
  for (int j = 0; j < 8; ++j) tmp[j] = f2bf(src[(size_t)(kc * 8 + j) * COUT]);
  ushort* dst = kernT + (((size_t)(ko * 4 + ct) * 16 + colq) * 32 + kc * 8);
#pragma unroll
  for (int j = 0; j < 8; ++j) dst[j] = tmp[j];
}

// ---------------------------------------------------------------------------
// histogram over k-major (k, block32) bins — 2 pairs per thread
// ---------------------------------------------------------------------------
__global__ __launch_bounds__(256) void hist_kernel(const int4* __restrict__ kmap2,
                                                   int* __restrict__ count,
                                                   int M2, int NB) {
  int t = blockIdx.x * 256 + threadIdx.x;
  int k = blockIdx.y;
  if (t < M2) {
    int4 v = kmap2[(size_t)k * M2 + t];
    atomicAdd(&count[k * NB + (v.y >> 5)], 1);
    atomicAdd(&count[k * NB + (v.w >> 5)], 1);
  }
}

// ---------------------------------------------------------------------------
// scan (3 kernels) — verified rounds 2-5
// ---------------------------------------------------------------------------
__global__ __launch_bounds__(256) void scan_reduce(const int* __restrict__ count,
                                                   int* __restrict__ partial, int nb) {
  __shared__ int ws[4];
  int t = threadIdx.x;
  int base = blockIdx.x * SCAN_CHUNK + t * 16;
  int s = 0;
#pragma unroll
  for (int i = 0; i < 16; ++i) { int idx = base + i; if (idx < nb) s += count[idx]; }
  for (int d = 32; d; d >>= 1) s += __shfl_down(s, d);
  if ((t & 63) == 0) ws[t >> 6] = s;
  __syncthreads();
  if (t == 0) partial[blockIdx.x] = ws[0] + ws[1] + ws[2] + ws[3];
}

__global__ __launch_bounds__(64) void scan_partials(int* __restrict__ partial,
                                                    int nchunks, int* __restrict__ total_out) {
  int lane = threadIdx.x;
  int run = 0;
  for (int base = 0; base < nchunks; base += 64) {
    int i = base + lane;
    int orig = (i < nchunks) ? partial[i] : 0;
    int v = orig;
    for (int d = 1; d < 64; d <<= 1) { int u = __shfl_up(v, d); if (lane >= d) v += u; }
    if (i < nchunks) partial[i] = run + v - orig;
    run += __shfl(v, 63);
  }
  if (lane == 0) *total_out = run;
}

__global__ __launch_bounds__(256) void scan_down(const int* __restrict__ count,
                                                 const int* __restrict__ partial,
                                                 int* __restrict__ start,
                                                 int* __restrict__ cursor, int nb) {
  __shared__ int wsum[4];
  int t = threadIdx.x, blk = blockIdx.x;
  int base = blk * SCAN_CHUNK + t * 16;
  int v[16]; int s = 0;
#pragma unroll
  for (int i = 0; i < 16; ++i) { int idx = base + i; v[i] = (idx < nb) ? count[idx] : 0; s += v[i]; }
  int lane = t & 63, wv = t >> 6;
  int sv = s;
  for (int d = 1; d < 64; d <<= 1) { int u = __shfl_up(sv, d); if (lane >= d) sv += u; }
  if (lane == 63) wsum[wv] = sv;
  __syncthreads();
  int wbase = 0;
  for (int i = 0; i < wv; ++i) wbase += wsum[i];
  int prefix = partial[blk] + wbase + (sv - s);
#pragma unroll
  for (int i = 0; i < 16; ++i) {
    int idx = base + i;
    if (idx < nb) { start[idx] = prefix; cursor[idx] = prefix; }
    prefix += v[i];
  }
}

// ---------------------------------------------------------------------------
// scatter into k-major bins: entry = in_idx(18b) | rowlocal(5b)<<18
// cursor atomics hit a 25KB window, binned writes a 400KB window per k
// ---------------------------------------------------------------------------
__global__ __launch_bounds__(256) void scatter_kernel(const int4* __restrict__ kmap2,
                                                      int* __restrict__ cursor,
                                                      uint32_t* __restrict__ binned,
                                                      int M2, int NB) {
  int t = blockIdx.x * 256 + threadIdx.x;
  int k = blockIdx.y;
  if (t < M2) {
    int4 v = kmap2[(size_t)k * M2 + t];
    int p1 = atomicAdd(&cursor[k * NB + (v.y >> 5)], 1);
    binned[p1] = (uint32_t)v.x | ((uint32_t)(v.y & 31) << 18);
    int p2 = atomicAdd(&cursor[k * NB + (v.w >> 5)], 1);
    binned[p2] = (uint32_t)v.z | ((uint32_t)(v.w & 31) << 18);
  }
}

// ---------------------------------------------------------------------------
// main: 1 wave per 32 output rows. Per k (avg 16 entries = 1 full batch):
//   gather 16 feat rows (lane (g,q): entry q, chunk g) -> cvt_pk bf16
//   C1 = F @ W[k]  (4x mfma_f32_16x16x32_bf16; rows = entry slots)
//   lane holds C1[4g+reg][q]; 4 shfl give row targets; 16 ds_add_f32 into the
//   per-wave [32][66] tile. NOTHING reads the tile until the epilogue ->
//   no lgkmcnt drain in the loop; waves free-flow. Invalid slots have A-row
//   zeroed so their atomics add 0.0. Next k's entries prefetched one ahead.
// ---------------------------------------------------------------------------
__global__ __launch_bounds__(WPG * 64) void conv_mfma4(
    const float* __restrict__ feat,       // [N][CIN] f32
    const uint32_t* __restrict__ binned,  // [E] k-major
    const int* __restrict__ start,        // [NBIN+1] k-major
    const ushort* __restrict__ kernT,     // [KVOL][4][16][32] bf16
    const float* __restrict__ bias,       // [COUT]
    float* __restrict__ out,              // [N][COUT]
    int NB) {                             // N/RB bins per k
  __shared__ float tile[WPG][RB][TSTRIDE];
  const int wv = threadIdx.x >> 6;
  const int l  = threadIdx.x & 63;
  const int q  = l & 15;          // entry slot / cout-within-tile
  const int g  = l >> 4;          // feat chunk / D row group
  const int blk = blockIdx.x * WPG + wv;

  float* tw = &tile[wv][0][0];
  {
    const float2 z2 = {0.f, 0.f};
    for (int i = l; i < RB * TSTRIDE / 2; i += 64) ((float2*)tw)[i] = z2;
  }

  // segment bounds for all 27 k's: lane k holds [sv_k, sw_k)
  int sv = 0, sw = 0;
  if (l < KVOL) {
    sv = start[l * NB + blk];
    sw = start[l * NB + blk + 1];
  }

  asm volatile("s_waitcnt lgkmcnt(0)" ::: "memory");   // tile zeros done
  __builtin_amdgcn_sched_barrier(0);

  // prefetch entry words for k=0
  int sb_cur = __shfl(sv, 0);
  int cnt_cur = __shfl(sw, 0) - sb_cur;
  uint32_t e_cur = 0;
  if (cnt_cur > 0) {
    int cb0 = cnt_cur < 16 ? cnt_cur : 16;
    e_cur = binned[sb_cur + (q < cb0 ? q : 0)];
  }

  for (int k = 0; k < KVOL; ++k) {
    // prefetch next k's entry words (independent of this k's compute)
    int sb_nxt = 0, cnt_nxt = 0; uint32_t e_nxt = 0;
    if (k + 1 < KVOL) {
      sb_nxt = __shfl(sv, k + 1);
      cnt_nxt = __shfl(sw, k + 1) - sb_nxt;
      if (cnt_nxt > 0) {
        int cbn = cnt_nxt < 16 ? cnt_nxt : 16;
        e_nxt = binned[sb_nxt + (q < cbn ? q : 0)];
      }
    }

    if (cnt_cur > 0) {
      // W[k] B-fragments (L2-resident, 4x16B)
      const ushort* kb = kernT + ((size_t)k * 64 + q) * 32 + g * 8;
      bf16x8 b0 = *(const bf16x8*)(kb);
      bf16x8 b1 = *(const bf16x8*)(kb + 512);
      bf16x8 b2 = *(const bf16x8*)(kb + 1024);
      bf16x8 b3 = *(const bf16x8*)(kb + 1536);

      uint32_t e = e_cur;
      for (int base = 0; base < cnt_cur; base += 16) {
        int cb = cnt_cur - base; if (cb > 16) cb = 16;
        if (base) e = binned[sb_cur + base + (q < cb ? q : 0)];  // cnt>16 tail

        // gather: lane (q,g) reads feat[in(entry q)][8g..8g+8)
        const float* fp = feat + (size_t)(e & 0x3FFFFu) * CIN + g * 8;
        float4 f0 = *(const float4*)fp;
        float4 f1 = *(const float4*)(fp + 4);
        u32x4 ua;
        ua.x = cvtpk(f0.x, f0.y); ua.y = cvtpk(f0.z, f0.w);
        ua.z = cvtpk(f1.x, f1.y); ua.w = cvtpk(f1.z, f1.w);
        if (q >= cb) { ua.x = 0; ua.y = 0; ua.z = 0; ua.w = 0; }  // zero pad rows
        bf16x8 a = __builtin_bit_cast(bf16x8, ua);

        f32x4 z = {0.f, 0.f, 0.f, 0.f};
        f32x4 c10 = __builtin_amdgcn_mfma_f32_16x16x32_bf16(a, b0, z, 0, 0, 0);
        f32x4 c11 = __builtin_amdgcn_mfma_f32_16x16x32_bf16(a, b1, z, 0, 0, 0);
        f32x4 c12 = __builtin_amdgcn_mfma_f32_16x16x32_bf16(a, b2, z, 0, 0, 0);
        f32x4 c13 = __builtin_amdgcn_mfma_f32_16x16x32_bf16(a, b3, z, 0, 0, 0);

        // row targets for my 4 D-rows (entries 4g+0..3); pad rows add 0.0
        int rl0 = (__shfl((int)e, 4 * g + 0) >> 18) & 31;
        int rl1 = (__shfl((int)e, 4 * g + 1) >> 18) & 31;
        int rl2 = (__shfl((int)e, 4 * g + 2) >> 18) & 31;
        int rl3 = (__shfl((int)e, 4 * g + 3) >> 18) & 31;

        float* p0 = tw + rl0 * TSTRIDE + q;
        atomicAdd(p0,      c10[0]); atomicAdd(p0 + 16, c11[0]);
        atomicAdd(p0 + 32, c12[0]); atomicAdd(p0 + 48, c13[0]);
        float* p1 = tw + rl1 * TSTRIDE + q;
        atomicAdd(p1,      c10[1]); atomicAdd(p1 + 16, c11[1]);
        atomicAdd(p1 + 32, c12[1]); atomicAdd(p1 + 48, c13[1]);
        float* p2 = tw + rl2 * TSTRIDE + q;
        atomicAdd(p2,      c10[2]); atomicAdd(p2 + 16, c11[2]);
        atomicAdd(p2 + 32, c12[2]); atomicAdd(p2 + 48, c13[2]);
        float* p3 = tw + rl3 * TSTRIDE + q;
        atomicAdd(p3,      c10[3]); atomicAdd(p3 + 16, c11[3]);
        atomicAdd(p3 + 32, c12[3]); atomicAdd(p3 + 48, c13[3]);
      }
    }
    sb_cur = sb_nxt; cnt_cur = cnt_nxt; e_cur = e_nxt;
  }

  asm volatile("s_waitcnt lgkmcnt(0)" ::: "memory");   // all ds_adds done
  __builtin_amdgcn_sched_barrier(0);

  // epilogue: lane l = cout channel; 32 rows, coalesced 256B stores
  const float bv = bias[l];
  const int R0 = blk * RB;
#pragma unroll 4
  for (int r = 0; r < RB; ++r)
    out[(size_t)(R0 + r) * COUT + l] = tw[r * TSTRIDE + l] + bv;
}

// ---------------------------------------------------------------------------
extern "C" void kernel_launch(void* const* d_in, const int* in_sizes, int n_in,
                              void* d_out, int out_size, void* d_ws, size_t ws_size,
                              hipStream_t stream) {
  const float* feat  = (const float*)d_in[0];
  const int4*  kmap2 = (const int4*)d_in[3];   // 2 pairs per int4
  const float* kern  = (const float*)d_in[4];
  const float* bias  = (const float*)d_in[5];
  float* out = (float*)d_out;

  const int N = in_sizes[0] / CIN;            // 200000
  const int M = in_sizes[3] / (2 * KVOL);     // 100000
  const int M2 = M / 2;                       // 50000
  const int NB = N / RB;                      // 6250
  const int NBIN = NB * KVOL;                 // 168750

  // workspace
  ushort* kernT = (ushort*)d_ws;                        // 55296 ushorts
  int* count    = (int*)(kernT + (size_t)KVOL * CIN * COUT);
  int* startA   = count + NBIN;                         // NBIN+1
  int* cursor   = startA + NBIN + 1;
  int* partial  = cursor + NBIN;                        // 128
  uint32_t* binned = (uint32_t*)(partial + 128);        // KVOL*M

  const int nchunks = (NBIN + SCAN_CHUNK - 1) / SCAN_CHUNK;   // 42

  hipMemsetAsync(count, 0, (size_t)NBIN * sizeof(int), stream);
  hipLaunchKernelGGL(kern_cvt_kernel, dim3(KVOL), dim3(256), 0, stream, kern, kernT);

  dim3 pgrid((M2 + 255) / 256, KVOL);
  hipLaunchKernelGGL(hist_kernel, pgrid, dim3(256), 0, stream, kmap2, count, M2, NB);
  hipLaunchKernelGGL(scan_reduce, dim3(nchunks), dim3(256), 0, stream, count, partial, NBIN);
  hipLaunchKernelGGL(scan_partials, dim3(1), dim3(64), 0, stream, partial, nchunks, startA + NBIN);
  hipLaunchKernelGGL(scan_down, dim3(nchunks), dim3(256), 0, stream,
                     count, partial, startA, cursor, NBIN);
  hipLaunchKernelGGL(scatter_kernel, pgrid, dim3(256), 0, stream, kmap2, cursor, binned, M2, NB);

  hipLaunchKernelGGL(conv_mfma4, dim3(NB / WPG), dim3(WPG * 64), 0, stream,
                     feat, binned, startA, kernT, bias, out, NB);
}